// Round 2
// baseline (804.059 us; speedup 1.0000x reference)
//
#include <hip/hip_runtime.h>
#include <hip/hip_fp16.h>
#include <stdint.h>

// ---------------------------------------------------------------------------
// Linear_90701119356941: out = x @ W^T + bias,
//   W[o,i] = sum_q softmax(alpha[o,i,:] + gumbel(key42))[q] * quant_vals[q]
// Stages: (1) gen W (threefry gumbel softmax) -> fp16 ws
//         (2) cast x f32 -> fp16 ws
//         (3) MFMA GEMM (m97 structure, 128x128 tile, 16x16x32_f16)
// PRNG: JAX threefry2x32. PRNG_PARTITIONABLE=1 reproduces the modern JAX
// default (bits = o0^o1 of threefry(key,(hi(e),lo(e)))). Set to 0 for the
// legacy concatenated-halves mode if validation fails.
// ---------------------------------------------------------------------------

#define PRNG_PARTITIONABLE 1

#define OUT_F 4096
#define IN_F  4096
#define MROWS 8192   // B*S = 4*2048
#define NQV   3

typedef __attribute__((ext_vector_type(4))) _Float16 f16x4;
typedef __attribute__((ext_vector_type(8))) _Float16 f16x8;
typedef __attribute__((ext_vector_type(4))) float    f32x4;

__device__ __forceinline__ uint32_t rotl32(uint32_t x, int r) {
  return (x << r) | (x >> (32 - r));
}

// JAX threefry2x32, key = jax.random.key(42) -> data (0, 42)
__device__ __forceinline__ void threefry2x32(uint32_t x0, uint32_t x1,
                                             uint32_t& o0, uint32_t& o1) {
  const uint32_t ks0 = 0u, ks1 = 42u;
  const uint32_t ks2 = ks0 ^ ks1 ^ 0x1BD11BDAu;
  x0 += ks0; x1 += ks1;
#define TF_R(r) { x0 += x1; x1 = rotl32(x1, r); x1 ^= x0; }
  TF_R(13) TF_R(15) TF_R(26) TF_R(6)
  x0 += ks1; x1 += ks2 + 1u;
  TF_R(17) TF_R(29) TF_R(16) TF_R(24)
  x0 += ks2; x1 += ks0 + 2u;
  TF_R(13) TF_R(15) TF_R(26) TF_R(6)
  x0 += ks0; x1 += ks1 + 3u;
  TF_R(17) TF_R(29) TF_R(16) TF_R(24)
  x0 += ks1; x1 += ks2 + 4u;
  TF_R(13) TF_R(15) TF_R(26) TF_R(6)
  x0 += ks2; x1 += ks0 + 5u;
#undef TF_R
  o0 = x0; o1 = x1;
}

// random 32-bit word for flat element index e (N = 4096*4096*3 elements)
__device__ __forceinline__ uint32_t rand_word(uint32_t e) {
#if PRNG_PARTITIONABLE
  // counts = iota(u64); x0 = hi32(e) = 0, x1 = lo32(e); bits = o0 ^ o1
  uint32_t o0, o1;
  threefry2x32(0u, e, o0, o1);
  return o0 ^ o1;
#else
  // legacy: counts = iota(u32, N); pairs (i, i+H), out = concat(o0, o1)
  const uint32_t H = (uint32_t)(OUT_F) * IN_F * NQV / 2u;  // 25165824
  uint32_t o0, o1;
  if (e < H) { threefry2x32(e, e + H, o0, o1); return o0; }
  else       { threefry2x32(e - H, e, o0, o1); return o1; }
#endif
}

// g = -log(-log(max(tiny, (bits>>9|1.0f bits) - 1 + tiny)))
__device__ __forceinline__ float gumbel_bits(uint32_t bits) {
  float f = __uint_as_float(0x3f800000u | (bits >> 9)) - 1.0f;
  const float tiny = 1.17549435e-38f;
  float u = fmaxf(tiny, f + tiny);
  return -__logf(-__logf(u));
}

// ---------------------------------------------------------------------------
// Kernel 1: W[o,i] = sum_q softmax(alpha+g)[q]*qv[q]  -> fp16
// thread handles 4 (o,i) positions: 3 float4 alpha loads, 4 fp16 out (8B)
// ---------------------------------------------------------------------------
__global__ __launch_bounds__(256) void gen_w_kernel(
    const float* __restrict__ alpha, const float* __restrict__ qv,
    _Float16* __restrict__ Wh) {
  int t = blockIdx.x * 256 + threadIdx.x;     // 0 .. 4194303
  int oi0 = t << 2;
  const float4* ap = (const float4*)(alpha + (size_t)oi0 * 3);
  float4 v0 = ap[0], v1 = ap[1], v2 = ap[2];
  float a[12] = {v0.x, v0.y, v0.z, v0.w, v1.x, v1.y, v1.z, v1.w,
                 v2.x, v2.y, v2.z, v2.w};
  float q0 = qv[0], q1 = qv[1], q2 = qv[2];
  f16x4 wv;
#pragma unroll
  for (int j = 0; j < 4; ++j) {
    uint32_t e = (uint32_t)(oi0 + j) * 3u;
    float s0 = a[3 * j + 0] + gumbel_bits(rand_word(e));
    float s1 = a[3 * j + 1] + gumbel_bits(rand_word(e + 1u));
    float s2 = a[3 * j + 2] + gumbel_bits(rand_word(e + 2u));
    float mx = fmaxf(s0, fmaxf(s1, s2));
    float e0 = __expf(s0 - mx), e1 = __expf(s1 - mx), e2 = __expf(s2 - mx);
    float w = (e0 * q0 + e1 * q1 + e2 * q2) / (e0 + e1 + e2);
    wv[j] = (_Float16)w;
  }
  *(f16x4*)(Wh + oi0) = wv;
}

// ---------------------------------------------------------------------------
// Kernel 2: x f32 -> fp16 (8 elems/thread)
// ---------------------------------------------------------------------------
__global__ __launch_bounds__(256) void cast_x_kernel(
    const float* __restrict__ X, _Float16* __restrict__ Xh) {
  size_t i = ((size_t)blockIdx.x * 256 + threadIdx.x) << 3;
  float4 v0 = *(const float4*)(X + i);
  float4 v1 = *(const float4*)(X + i + 4);
  f16x8 r;
  r[0] = (_Float16)v0.x; r[1] = (_Float16)v0.y;
  r[2] = (_Float16)v0.z; r[3] = (_Float16)v0.w;
  r[4] = (_Float16)v1.x; r[5] = (_Float16)v1.y;
  r[6] = (_Float16)v1.z; r[7] = (_Float16)v1.w;
  *(f16x8*)(Xh + i) = r;
}

// ---------------------------------------------------------------------------
// Kernel 3: GEMM C[m][n] = sum_k X[m][k]*W[n][k] + bias[n]
// m97 structure: 128x128 tile, BK=32, 4 waves (2x2), 4x4 frags of 16x16x32
// global_load_lds width=16 staging, 2-barrier K-loop, XCD swizzle.
// ---------------------------------------------------------------------------
#define BM 128
#define BN 128
#define BK 32
#define NTILES_N (OUT_F / BN)  // 32

__global__ __launch_bounds__(256) void gemm_kernel(
    const _Float16* __restrict__ X, const _Float16* __restrict__ W,
    const float* __restrict__ bias, float* __restrict__ C) {
  __shared__ __align__(16) _Float16 As[BM * BK];
  __shared__ __align__(16) _Float16 Bs[BN * BK];

  int tid = threadIdx.x;
  int wid = tid >> 6, lane = tid & 63;

  // bijective XCD swizzle (nwg = 2048, divisible by 8)
  int nwg = gridDim.x;
  int q = nwg >> 3;
  int wg = (blockIdx.x & 7) * q + (blockIdx.x >> 3);
  int mt = wg / NTILES_N, nt = wg % NTILES_N;
  int m0 = mt * BM, n0 = nt * BN;

  int wm = wid >> 1, wn = wid & 1;
  int lr = lane & 15, kg = lane >> 4;

  // fragment element offsets in LDS (row-major [128][32], k-contig)
  int aoff[4], boff[4];
#pragma unroll
  for (int f = 0; f < 4; ++f) {
    aoff[f] = (wm * 64 + f * 16 + lr) * BK + kg * 8;
    boff[f] = (wn * 64 + f * 16 + lr) * BK + kg * 8;
  }

  f32x4 acc[4][4] = {};

  // staging: 512 16B segments per tile; thread t does seg t and t+256.
  // LDS dest must be the wave-uniform base (HW adds lane*16).
  int srow0 = tid >> 2, scol0 = (tid & 3) * 8;
  int srow1 = (tid + 256) >> 2, scol1 = ((tid + 256) & 3) * 8;
  int ldsb0 = (wid * 64) * 8;            // elements, round 0
  int ldsb1 = (256 + wid * 64) * 8;      // elements, round 1

#define STAGE(k0)                                                             \
  {                                                                           \
    const _Float16* gA0 = X + (size_t)(m0 + srow0) * IN_F + (k0) + scol0;     \
    const _Float16* gB0 = W + (size_t)(n0 + srow0) * IN_F + (k0) + scol0;     \
    const _Float16* gA1 = X + (size_t)(m0 + srow1) * IN_F + (k0) + scol1;     \
    const _Float16* gB1 = W + (size_t)(n0 + srow1) * IN_F + (k0) + scol1;     \
    __builtin_amdgcn_global_load_lds(                                         \
        (const __attribute__((address_space(1))) void*)gA0,                   \
        (__attribute__((address_space(3))) void*)(As + ldsb0), 16, 0, 0);     \
    __builtin_amdgcn_global_load_lds(                                         \
        (const __attribute__((address_space(1))) void*)gB0,                   \
        (__attribute__((address_space(3))) void*)(Bs + ldsb0), 16, 0, 0);     \
    __builtin_amdgcn_global_load_lds(                                         \
        (const __attribute__((address_space(1))) void*)gA1,                   \
        (__attribute__((address_space(3))) void*)(As + ldsb1), 16, 0, 0);     \
    __builtin_amdgcn_global_load_lds(                                         \
        (const __attribute__((address_space(1))) void*)gB1,                   \
        (__attribute__((address_space(3))) void*)(Bs + ldsb1), 16, 0, 0);     \
  }

  STAGE(0)

#pragma unroll 1
  for (int kt = 0; kt < IN_F / BK; ++kt) {
    __syncthreads();  // drains vmcnt: staged tile complete & visible
    f16x8 af[4], bf[4];
#pragma unroll
    for (int f = 0; f < 4; ++f) {
      af[f] = *(const f16x8*)(As + aoff[f]);
      bf[f] = *(const f16x8*)(Bs + boff[f]);
    }
#pragma unroll
    for (int i = 0; i < 4; ++i)
#pragma unroll
      for (int j = 0; j < 4; ++j)
        acc[i][j] =
            __builtin_amdgcn_mfma_f32_16x16x32_f16(af[i], bf[j], acc[i][j], 0, 0, 0);
    __syncthreads();  // all waves done reading before overwrite
    if (kt + 1 < IN_F / BK) STAGE((kt + 1) * BK)
  }
#undef STAGE

  // epilogue: C/D layout col = lane&15, row = (lane>>4)*4 + r
#pragma unroll
  for (int j = 0; j < 4; ++j) {
    int col = n0 + wn * 64 + j * 16 + lr;
    float bv = bias[col];
#pragma unroll
    for (int i = 0; i < 4; ++i) {
      int row0 = m0 + wm * 64 + i * 16 + kg * 4;
#pragma unroll
      for (int r = 0; r < 4; ++r)
        C[(size_t)(row0 + r) * OUT_F + col] = acc[i][j][r] + bv;
    }
  }
}

// ---------------------------------------------------------------------------
extern "C" void kernel_launch(void* const* d_in, const int* in_sizes, int n_in,
                              void* d_out, int out_size, void* d_ws,
                              size_t ws_size, hipStream_t stream) {
  const float* x     = (const float*)d_in[0];
  const float* alpha = (const float*)d_in[1];
  const float* qv    = (const float*)d_in[2];
  const float* bias  = (const float*)d_in[3];
  float* out = (float*)d_out;

  // ws layout: W fp16 (32 MiB) | X fp16 (64 MiB)  -> needs ~100.7 MB
  _Float16* Wh = (_Float16*)d_ws;
  _Float16* Xh = (_Float16*)((char*)d_ws + (size_t)OUT_F * IN_F * sizeof(_Float16));

  gen_w_kernel<<<dim3((OUT_F * IN_F) / (256 * 4)), dim3(256), 0, stream>>>(alpha, qv, Wh);
  cast_x_kernel<<<dim3(((size_t)MROWS * IN_F) / (256 * 8)), dim3(256), 0, stream>>>(x, Xh);
  gemm_kernel<<<dim3((MROWS / BM) * (OUT_F / BN)), dim3(256), 0, stream>>>(Xh, Wh, bias, out);
}

// Round 5
// 660.656 us; speedup vs baseline: 1.2171x; 1.2171x over previous
//
#include <hip/hip_runtime.h>
#include <hip/hip_fp16.h>
#include <stdint.h>

// ---------------------------------------------------------------------------
// Linear_90701119356941: out = x @ W^T + bias,
//   W[o,i] = sum_q softmax(alpha[o,i,:] + gumbel(key42))[q] * quant_vals[q]
// Stage 1 (prep): gen W fp16 + cast x fp16 (fused, one launch)
// Stage 2 (gemm): 256x256 tile, BK=32, 3-deep LDS pipeline, counted vmcnt,
//                 XOR-swizzled LDS, raw s_barrier phases, setprio (T2-T5).
// ---------------------------------------------------------------------------

#define PRNG_PARTITIONABLE 1

#define OUT_F 4096
#define IN_F  4096
#define MROWS 8192   // B*S
#define NQV   3

typedef __attribute__((ext_vector_type(4))) _Float16 f16x4;
typedef __attribute__((ext_vector_type(8))) _Float16 f16x8;
typedef __attribute__((ext_vector_type(4))) float    f32x4;

__device__ __forceinline__ uint32_t rotl32(uint32_t x, int r) {
  return (x << r) | (x >> (32 - r));
}

// JAX threefry2x32, key = jax.random.key(42) -> (0, 42)   [validated R2]
__device__ __forceinline__ void threefry2x32(uint32_t x0, uint32_t x1,
                                             uint32_t& o0, uint32_t& o1) {
  const uint32_t ks0 = 0u, ks1 = 42u;
  const uint32_t ks2 = ks0 ^ ks1 ^ 0x1BD11BDAu;
  x0 += ks0; x1 += ks1;
#define TF_R(r) { x0 += x1; x1 = rotl32(x1, r); x1 ^= x0; }
  TF_R(13) TF_R(15) TF_R(26) TF_R(6)
  x0 += ks1; x1 += ks2 + 1u;
  TF_R(17) TF_R(29) TF_R(16) TF_R(24)
  x0 += ks2; x1 += ks0 + 2u;
  TF_R(13) TF_R(15) TF_R(26) TF_R(6)
  x0 += ks0; x1 += ks1 + 3u;
  TF_R(17) TF_R(29) TF_R(16) TF_R(24)
  x0 += ks1; x1 += ks2 + 4u;
  TF_R(13) TF_R(15) TF_R(26) TF_R(6)
  x0 += ks2; x1 += ks0 + 5u;
#undef TF_R
  o0 = x0; o1 = x1;
}

__device__ __forceinline__ uint32_t rand_word(uint32_t e) {
#if PRNG_PARTITIONABLE
  uint32_t o0, o1;
  threefry2x32(0u, e, o0, o1);
  return o0 ^ o1;
#else
  const uint32_t H = (uint32_t)(OUT_F) * IN_F * NQV / 2u;
  uint32_t o0, o1;
  if (e < H) { threefry2x32(e, e + H, o0, o1); return o0; }
  else       { threefry2x32(e - H, e, o0, o1); return o1; }
#endif
}

__device__ __forceinline__ float gumbel_bits(uint32_t bits) {
  float f = __uint_as_float(0x3f800000u | (bits >> 9)) - 1.0f;
  const float tiny = 1.17549435e-38f;
  float u = fmaxf(tiny, f + tiny);
  return -__logf(-__logf(u));
}

// ---------------------------------------------------------------------------
// prep: blocks [0, 16384)  -> gen W (1024 oi per block, LDS-coalesced alpha)
//       blocks [16384, 32768) -> cast x f32->fp16 (2048 elems per block)
// ---------------------------------------------------------------------------
#define GW_BLOCKS 16384
__global__ __launch_bounds__(256) void prep_kernel(
    const float* __restrict__ alpha, const float* __restrict__ qv,
    const float* __restrict__ X, _Float16* __restrict__ Wh,
    _Float16* __restrict__ Xh) {
  __shared__ float sb[3072];
  int tid = threadIdx.x;
  int blk = blockIdx.x;
  if (blk < GW_BLOCKS) {
    // coalesced load of 3072 floats (12 KB chunk)
    const float4* g = (const float4*)(alpha + (size_t)blk * 3072);
    float4 v0 = g[tid], v1 = g[tid + 256], v2 = g[tid + 512];
    float4* s4 = (float4*)sb;
    s4[tid] = v0; s4[tid + 256] = v1; s4[tid + 512] = v2;
    __syncthreads();
    const float4* rp = (const float4*)(sb + tid * 12);
    float4 a0 = rp[0], a1 = rp[1], a2 = rp[2];
    float a[12] = {a0.x, a0.y, a0.z, a0.w, a1.x, a1.y, a1.z, a1.w,
                   a2.x, a2.y, a2.z, a2.w};
    float q0 = qv[0], q1 = qv[1], q2 = qv[2];
    int oi0 = blk * 1024 + tid * 4;
    uint32_t ebase = (uint32_t)blk * 3072u + (uint32_t)tid * 12u;
    f16x4 wv;
#pragma unroll
    for (int j = 0; j < 4; ++j) {
      uint32_t e = ebase + (uint32_t)(3 * j);
      float s0 = a[3 * j + 0] + gumbel_bits(rand_word(e));
      float s1 = a[3 * j + 1] + gumbel_bits(rand_word(e + 1u));
      float s2 = a[3 * j + 2] + gumbel_bits(rand_word(e + 2u));
      float mx = fmaxf(s0, fmaxf(s1, s2));
      float e0 = __expf(s0 - mx), e1 = __expf(s1 - mx), e2 = __expf(s2 - mx);
      float w = (e0 * q0 + e1 * q1 + e2 * q2) / (e0 + e1 + e2);
      wv[j] = (_Float16)w;
    }
    *(f16x4*)(Wh + oi0) = wv;
  } else {
    size_t i = (((size_t)(blk - GW_BLOCKS)) * 256 + tid) << 3;
    float4 v0 = *(const float4*)(X + i);
    float4 v1 = *(const float4*)(X + i + 4);
    f16x8 r;
    r[0] = (_Float16)v0.x; r[1] = (_Float16)v0.y;
    r[2] = (_Float16)v0.z; r[3] = (_Float16)v0.w;
    r[4] = (_Float16)v1.x; r[5] = (_Float16)v1.y;
    r[6] = (_Float16)v1.z; r[7] = (_Float16)v1.w;
    *(f16x8*)(Xh + i) = r;
  }
}

// ---------------------------------------------------------------------------
// GEMM: C[m][n] = sum_k X[m][k]*W[n][k] + bias[n]
// 256x256 tile, BK=32, 8 waves (2M x 4N), 512 threads, 96 KiB LDS (3 bufs).
// Pipeline: compute tile t from buf t%3 while staging tile t+2 into (t+2)%3.
// Main-loop wait = vmcnt(4) once per K-tile (tile t+1 landed), never 0.
// LDS swizzle: 16B slot = kg ^ ((row>>1)&3) -> perfectly balanced banks.
// ---------------------------------------------------------------------------
#define NT 128   // K tiles (4096/32)

__global__ __launch_bounds__(512, 2) void gemm_kernel(
    const _Float16* __restrict__ X, const _Float16* __restrict__ W,
    const float* __restrict__ bias, float* __restrict__ C) {
  __shared__ __align__(16) _Float16 lds[49152];  // 3 x (A 8192 + B 8192)

  int tid = threadIdx.x;
  int wid = tid >> 6, lane = tid & 63;
  int lr = lane & 15, kg = lane >> 4;
  int wm = wid >> 2, wn = wid & 3;

  // XCD swizzle: 512 blocks, 64 per XCD -> 4mt x 16nt region per XCD
  int bid = blockIdx.x;
  int wg = (bid & 7) * 64 + (bid >> 3);
  int mt = wg >> 4, nt = wg & 15;
  int m0 = mt * 256, n0 = nt * 256;

  // staging segment mapping: seg s = r*512+tid covers LDS elems s*8..s*8+7
  // (row = s>>2, slot = s&3); global k-block kb = slot ^ ((row>>1)&3)
  int s0 = tid, s1 = 512 + tid;
  int r0row = s0 >> 2, r0kb = (s0 & 3) ^ ((r0row >> 1) & 3);
  int r1row = s1 >> 2, r1kb = (s1 & 3) ^ ((r1row >> 1) & 3);
  int dst0 = (wid * 64) * 8;          // wave-uniform LDS elem base, round 0
  int dst1 = (512 + wid * 64) * 8;    // round 1

  const _Float16* Xb = X + (size_t)m0 * IN_F;
  const _Float16* Wb = W + (size_t)n0 * IN_F;

#define GLD(src, dstp)                                                        \
  __builtin_amdgcn_global_load_lds(                                           \
      (const __attribute__((address_space(1))) void*)(src),                   \
      (__attribute__((address_space(3))) void*)(dstp), 16, 0, 0)

#define STAGE_A(t, bufp) {                                                    \
    GLD(Xb + (size_t)r0row * IN_F + (t) * 32 + r0kb * 8, (bufp) + dst0);      \
    GLD(Xb + (size_t)r1row * IN_F + (t) * 32 + r1kb * 8, (bufp) + dst1); }
#define STAGE_B(t, bufp) {                                                    \
    GLD(Wb + (size_t)r0row * IN_F + (t) * 32 + r0kb * 8, (bufp) + 8192 + dst0);\
    GLD(Wb + (size_t)r1row * IN_F + (t) * 32 + r1kb * 8, (bufp) + 8192 + dst1); }

  f32x4 acc[8][4] = {};
  int koff = (kg ^ ((lr >> 1) & 3)) * 8;  // swizzled 16B slot (elems)

  // prologue: stage tiles 0,1; wait tile 0 landed (vmcnt(4): tile1 in flight)
  STAGE_A(0, lds); STAGE_B(0, lds);
  STAGE_A(1, lds + 16384); STAGE_B(1, lds + 16384);
  asm volatile("s_waitcnt vmcnt(4)" ::: "memory");
  __builtin_amdgcn_s_barrier();

  int buf = 0;
#pragma unroll 1
  for (int t = 0; t < NT; ++t) {
    _Float16* Ab = lds + buf * 16384;
    _Float16* Bb = Ab + 8192;
    int nbuf = buf + 2; if (nbuf >= 3) nbuf -= 3;
    _Float16* Nb = lds + nbuf * 16384;

    f16x8 af[4], bf[4];
    // ---------------- phase 0 (rows wm*128 + 0..63) ----------------
#pragma unroll
    for (int f = 0; f < 4; ++f)
      af[f] = *(const f16x8*)(Ab + (wm * 128 + f * 16 + lr) * 32 + koff);
#pragma unroll
    for (int g = 0; g < 4; ++g)
      bf[g] = *(const f16x8*)(Bb + (wn * 64 + g * 16 + lr) * 32 + koff);
    if (t + 2 < NT) STAGE_A(t + 2, Nb);
    __builtin_amdgcn_s_barrier();
    asm volatile("s_waitcnt lgkmcnt(0)" ::: "memory");
    __builtin_amdgcn_sched_barrier(0);
    __builtin_amdgcn_s_setprio(1);
#pragma unroll
    for (int f = 0; f < 4; ++f)
#pragma unroll
      for (int g = 0; g < 4; ++g)
        acc[f][g] = __builtin_amdgcn_mfma_f32_16x16x32_f16(af[f], bf[g],
                                                           acc[f][g], 0, 0, 0);
    __builtin_amdgcn_s_setprio(0);
    __builtin_amdgcn_s_barrier();

    // ---------------- phase 1 (rows wm*128 + 64..127) --------------
#pragma unroll
    for (int f = 0; f < 4; ++f)
      af[f] = *(const f16x8*)(Ab + (wm * 128 + 64 + f * 16 + lr) * 32 + koff);
    if (t + 2 < NT) {
      STAGE_B(t + 2, Nb);
      asm volatile("s_waitcnt vmcnt(4)" ::: "memory");  // tile t+1 landed
    } else if (t < NT - 1) {
      asm volatile("s_waitcnt vmcnt(0)" ::: "memory");  // drain tail once
    }
    __builtin_amdgcn_s_barrier();
    asm volatile("s_waitcnt lgkmcnt(0)" ::: "memory");
    __builtin_amdgcn_sched_barrier(0);
    __builtin_amdgcn_s_setprio(1);
#pragma unroll
    for (int f = 0; f < 4; ++f)
#pragma unroll
      for (int g = 0; g < 4; ++g)
        acc[4 + f][g] = __builtin_amdgcn_mfma_f32_16x16x32_f16(af[f], bf[g],
                                                               acc[4 + f][g],
                                                               0, 0, 0);
    __builtin_amdgcn_s_setprio(0);
    __builtin_amdgcn_s_barrier();

    buf = (buf + 1 == 3) ? 0 : buf + 1;
  }
#undef STAGE_A
#undef STAGE_B
#undef GLD

  // epilogue: C/D layout col = lane&15, row = (lane>>4)*4 + r  [validated R2]
#pragma unroll
  for (int g = 0; g < 4; ++g) {
    int col = n0 + wn * 64 + g * 16 + lr;
    float bv = bias[col];
#pragma unroll
    for (int f = 0; f < 8; ++f) {
      int row0 = m0 + wm * 128 + f * 16 + kg * 4;
#pragma unroll
      for (int r = 0; r < 4; ++r)
        C[(size_t)(row0 + r) * OUT_F + col] = acc[f][g][r] + bv;
    }
  }
}

// ---------------------------------------------------------------------------
extern "C" void kernel_launch(void* const* d_in, const int* in_sizes, int n_in,
                              void* d_out, int out_size, void* d_ws,
                              size_t ws_size, hipStream_t stream) {
  const float* x     = (const float*)d_in[0];
  const float* alpha = (const float*)d_in[1];
  const float* qv    = (const float*)d_in[2];
  const float* bias  = (const float*)d_in[3];
  float* out = (float*)d_out;

  _Float16* Wh = (_Float16*)d_ws;
  _Float16* Xh = (_Float16*)((char*)d_ws + (size_t)OUT_F * IN_F * sizeof(_Float16));

  prep_kernel<<<dim3(32768), dim3(256), 0, stream>>>(alpha, qv, x, Wh, Xh);
  gemm_kernel<<<dim3((MROWS / 256) * (OUT_F / 256)), dim3(512), 0, stream>>>(
      Xh, Wh, bias, out);
}